// Round 1
// baseline (871.319 us; speedup 1.0000x reference)
//
#include <hip/hip_runtime.h>

typedef __bf16 bf16_t;
typedef __bf16 bf16x8 __attribute__((ext_vector_type(8)));
typedef float f32x16 __attribute__((ext_vector_type(16)));
typedef float f32x4 __attribute__((ext_vector_type(4)));

#define NROWS 1048576
#define NTILES (NROWS / 32)   // 32 batch rows per wave-tile

__device__ __forceinline__ float fast_sigmoid(float v) {
    float e = __builtin_amdgcn_exp2f(v * -1.44269504088896340736f);
    return __builtin_amdgcn_rcpf(1.0f + e);
}
__device__ __forceinline__ float fast_tanh(float v) {
    // tanh(v) = 1 - 2/(1+e^{2v})
    float e = __builtin_amdgcn_exp2f(v * 2.88539008177792681472f);
    return 1.0f - 2.0f * __builtin_amdgcn_rcpf(1.0f + e);
}

// Everything computed transposed:  D[n][m] = sum_k W[k][n] * X[m][k]
//   A-operand = W^T  (staged in LDS, pre-swizzled to fragment order)
//   B-operand = X^T  (lane l holds batch row m = l&31, k = (l>>5)*8 + j, contiguous)
//   C/D 32x32 layout: col(lane&31) = batch row m, row = (reg&3)+8*(reg>>2)+4*(lane>>5) = n
__global__ __launch_bounds__(256, 2) void gru_mfma(
    const float* __restrict__ x, const float* __restrict__ hx,
    const float* __restrict__ w_ir, const float* __restrict__ w_hr,
    const float* __restrict__ w_iz, const float* __restrict__ w_hz,
    const float* __restrict__ w_in, const float* __restrict__ w_hn,
    const float* __restrict__ b_r, const float* __restrict__ b_z,
    const float* __restrict__ b_n, float* __restrict__ out)
{
    // Weights as A-fragments, lane-major contiguous: frag index ((mat*2+t)*4+ks)*64+lane
    __shared__ bf16_t wA[6 * 4096];
    __shared__ float bias[3 * 64];

    const int tid = threadIdx.x;

    {   // stage weights: wA holds W^T in exact MFMA A-frag order (conflict-free b128 reads)
        const float* ws[6] = {w_ir, w_hr, w_iz, w_hz, w_in, w_hn};
        #pragma unroll
        for (int m = 0; m < 6; ++m) {
            const float* W = ws[m];
            for (int idx = tid; idx < 4096; idx += 256) {
                int k = idx >> 6;       // W is (k, n) row-major
                int n = idx & 63;
                int t  = n >> 5;        // n-tile
                int ks = k >> 4;        // K-step
                int ln = (n & 31) | (((k >> 3) & 1) << 5);  // lane holding this elem
                int j  = k & 7;
                wA[(((m * 2 + t) * 4 + ks) << 9) + (ln << 3) + j] = (bf16_t)W[idx];
            }
        }
        if (tid < 64) {
            bias[tid]       = b_r[tid];
            bias[64 + tid]  = b_z[tid];
            bias[128 + tid] = b_n[tid];
        }
    }
    __syncthreads();   // only barrier; main loop is barrier-free

    const int lane = tid & 63;
    const int wave = blockIdx.x * 4 + (tid >> 6);
    const int nwaves = gridDim.x * 4;
    const int m31 = lane & 31;   // batch row within tile (MFMA col)
    const int e = lane >> 5;     // k-half selector
    const bool ehi = (e != 0);
    const bf16x8* wAf = (const bf16x8*)wA;

    for (int tile = wave; tile < NTILES; tile += nwaves) {
        const float* xrow = x  + (size_t)(tile * 32 + m31) * 64;
        const float* hrow = hx + (size_t)(tile * 32 + m31) * 64;

        // ---- global loads: B-frags (contiguous k) + hx in C-quad layout ----
        f32x4 xs[8], hs[8], hq[8];
        #pragma unroll
        for (int ks = 0; ks < 4; ++ks) {
            xs[2 * ks]     = *(const f32x4*)(xrow + ks * 16 + e * 8);
            xs[2 * ks + 1] = *(const f32x4*)(xrow + ks * 16 + e * 8 + 4);
            hs[2 * ks]     = *(const f32x4*)(hrow + ks * 16 + e * 8);
            hs[2 * ks + 1] = *(const f32x4*)(hrow + ks * 16 + e * 8 + 4);
        }
        #pragma unroll
        for (int t = 0; t < 2; ++t)
            #pragma unroll
            for (int qq = 0; qq < 4; ++qq)
                hq[t * 4 + qq] = *(const f32x4*)(hrow + t * 32 + qq * 8 + e * 4);

        // ---- convert to bf16 frags ----
        bf16x8 xf[4], hf[4];
        #pragma unroll
        for (int ks = 0; ks < 4; ++ks) {
            #pragma unroll
            for (int i = 0; i < 4; ++i) {
                xf[ks][i]     = (bf16_t)xs[2 * ks][i];
                xf[ks][i + 4] = (bf16_t)xs[2 * ks + 1][i];
                hf[ks][i]     = (bf16_t)hs[2 * ks][i];
                hf[ks][i + 4] = (bf16_t)hs[2 * ks + 1][i];
            }
        }

        // ---- stage 1: Rpre = x@w_ir + hx@w_hr + b_r  (transposed) ----
        f32x16 accR[2];
        #pragma unroll
        for (int t = 0; t < 2; ++t)
            #pragma unroll
            for (int qq = 0; qq < 4; ++qq) {
                f32x4 bq = *(const f32x4*)(bias + t * 32 + qq * 8 + e * 4);
                #pragma unroll
                for (int i = 0; i < 4; ++i) accR[t][qq * 4 + i] = bq[i];
            }
        #pragma unroll
        for (int ks = 0; ks < 4; ++ks) {
            #pragma unroll
            for (int t = 0; t < 2; ++t) {
                accR[t] = __builtin_amdgcn_mfma_f32_32x32x16_bf16(
                    wAf[((0 * 2 + t) * 4 + ks) * 64 + lane], xf[ks], accR[t], 0, 0, 0);
                accR[t] = __builtin_amdgcn_mfma_f32_32x32x16_bf16(
                    wAf[((1 * 2 + t) * 4 + ks) * 64 + lane], hf[ks], accR[t], 0, 0, 0);
            }
        }

        // ---- r = sigmoid(Rpre);  rh = r * hx  (C layout, fp32) ----
        f32x16 rh[2];
        #pragma unroll
        for (int t = 0; t < 2; ++t)
            #pragma unroll
            for (int reg = 0; reg < 16; ++reg)
                rh[t][reg] = fast_sigmoid(accR[t][reg]) * hq[t * 4 + (reg >> 2)][reg & 3];

        // ---- C-layout -> B-frag conversion for rh via lane-pair quad exchange ----
        // B-frag needs rh[m][k=16ks+8e+j]; C rows split in quads between lanes l, l^32.
        bf16x8 rhf[4];
        #pragma unroll
        for (int ks = 0; ks < 4; ++ks) {
            const int tk = ks >> 1, ksl = ks & 1;
            f32x4 qa, qb;
            #pragma unroll
            for (int i = 0; i < 4; ++i) {
                qa[i] = rh[tk][8 * ksl + i];       // regs for eC=0 quad
                qb[i] = rh[tk][8 * ksl + 4 + i];   // regs for eC=1 quad
            }
            f32x4 send, recvq;
            #pragma unroll
            for (int i = 0; i < 4; ++i) send[i] = ehi ? qa[i] : qb[i];
            #pragma unroll
            for (int i = 0; i < 4; ++i) recvq[i] = __shfl_xor(send[i], 32, 64);
            #pragma unroll
            for (int i = 0; i < 4; ++i) {
                float lo = ehi ? recvq[i] : qa[i];  // j = 0..3 (source eC=0)
                float hi = ehi ? qb[i] : recvq[i];  // j = 4..7 (source eC=1)
                rhf[ks][i]     = (bf16_t)lo;
                rhf[ks][i + 4] = (bf16_t)hi;
            }
        }

        // ---- stage 2: Npre = x@w_in + rh@w_hn + b_n ----
        f32x16 accN[2];
        #pragma unroll
        for (int t = 0; t < 2; ++t)
            #pragma unroll
            for (int qq = 0; qq < 4; ++qq) {
                f32x4 bq = *(const f32x4*)(bias + 128 + t * 32 + qq * 8 + e * 4);
                #pragma unroll
                for (int i = 0; i < 4; ++i) accN[t][qq * 4 + i] = bq[i];
            }
        #pragma unroll
        for (int ks = 0; ks < 4; ++ks) {
            #pragma unroll
            for (int t = 0; t < 2; ++t) {
                accN[t] = __builtin_amdgcn_mfma_f32_32x32x16_bf16(
                    wAf[((4 * 2 + t) * 4 + ks) * 64 + lane], xf[ks], accN[t], 0, 0, 0);
                accN[t] = __builtin_amdgcn_mfma_f32_32x32x16_bf16(
                    wAf[((5 * 2 + t) * 4 + ks) * 64 + lane], rhf[ks], accN[t], 0, 0, 0);
            }
        }

        // ---- stage 3 (last, to minimize liveness): Zpre = x@w_iz + hx@w_hz + b_z ----
        f32x16 accZ[2];
        #pragma unroll
        for (int t = 0; t < 2; ++t)
            #pragma unroll
            for (int qq = 0; qq < 4; ++qq) {
                f32x4 bq = *(const f32x4*)(bias + 64 + t * 32 + qq * 8 + e * 4);
                #pragma unroll
                for (int i = 0; i < 4; ++i) accZ[t][qq * 4 + i] = bq[i];
            }
        #pragma unroll
        for (int ks = 0; ks < 4; ++ks) {
            #pragma unroll
            for (int t = 0; t < 2; ++t) {
                accZ[t] = __builtin_amdgcn_mfma_f32_32x32x16_bf16(
                    wAf[((2 * 2 + t) * 4 + ks) * 64 + lane], xf[ks], accZ[t], 0, 0, 0);
                accZ[t] = __builtin_amdgcn_mfma_f32_32x32x16_bf16(
                    wAf[((3 * 2 + t) * 4 + ks) * 64 + lane], hf[ks], accZ[t], 0, 0, 0);
            }
        }

        // ---- epilogue: h = hx + z*(n - hx), coalesced f32x4 stores ----
        float* orow = out + (size_t)(tile * 32 + m31) * 64;
        #pragma unroll
        for (int t = 0; t < 2; ++t) {
            #pragma unroll
            for (int qq = 0; qq < 4; ++qq) {
                f32x4 res;
                #pragma unroll
                for (int i = 0; i < 4; ++i) {
                    float nn = fast_tanh(accN[t][qq * 4 + i]);
                    float zz = fast_sigmoid(accZ[t][qq * 4 + i]);
                    float hh = hq[t * 4 + qq][i];
                    res[i] = hh + zz * (nn - hh);
                }
                *(f32x4*)(orow + t * 32 + qq * 8 + e * 4) = res;
            }
        }
    }
}

extern "C" void kernel_launch(void* const* d_in, const int* in_sizes, int n_in,
                              void* d_out, int out_size, void* d_ws, size_t ws_size,
                              hipStream_t stream) {
    const float* x    = (const float*)d_in[0];
    const float* hx   = (const float*)d_in[1];
    const float* w_ir = (const float*)d_in[2];
    const float* w_hr = (const float*)d_in[3];
    const float* w_iz = (const float*)d_in[4];
    const float* w_hz = (const float*)d_in[5];
    const float* w_in = (const float*)d_in[6];
    const float* w_hn = (const float*)d_in[7];
    const float* b_r  = (const float*)d_in[8];
    const float* b_z  = (const float*)d_in[9];
    const float* b_n  = (const float*)d_in[10];
    float* out = (float*)d_out;

    // 512 blocks = 2 blocks/CU (50 KB LDS each), 4 waves/block, 16 tiles/wave
    gru_mfma<<<512, 256, 0, stream>>>(x, hx, w_ir, w_hr, w_iz, w_hz,
                                      w_in, w_hn, b_r, b_z, b_n, out);
}